// Round 1
// baseline (11186.919 us; speedup 1.0000x reference)
//
#include <hip/hip_runtime.h>
#include <cstdint>
#include <cstddef>

static constexpr int NPTS  = 4096;
static constexpr int NB    = 8;
static constexpr int NROWS = NB * NPTS;      // 32768
static constexpr int KNN   = 32;

// ---------------- utility: 64-bit shfl_xor built from 32-bit ----------------
__device__ __forceinline__ unsigned long long shfl_xor_u64(unsigned long long v, int m) {
  int lo = __shfl_xor((int)(unsigned)(v & 0xFFFFFFFFULL), m, 64);
  int hi = __shfl_xor((int)(unsigned)(v >> 32), m, 64);
  return ((unsigned long long)(unsigned)hi << 32) | (unsigned)lo;
}

// ---------------- squared norms per point ----------------
__global__ __launch_bounds__(256) void sqnorm_kernel(const float* __restrict__ x,
                                                     float* __restrict__ sq, int F) {
  int t = blockIdx.x * 256 + threadIdx.x;
  if (t >= NROWS) return;
  const float* p = x + (size_t)t * F;
  float s = 0.f;
  for (int f = 0; f < F; ++f) s = fmaf(p[f], p[f], s);
  sq[t] = s;
}

// ---------------- fused dist + top-32 selection ----------------
// One wave per query row i (within its batch). Lane owns candidates
// j = c4*256 + 4*lane + s. Distributed top-32 list: lanes 0..31 each hold one
// entry packed as (key<<32)|(lane<<12)|idx. Streaming replace-max insertion.
template <int F>
__global__ __launch_bounds__(256) void knn_kernel(const float* __restrict__ x,
                                                  const float* __restrict__ sq,
                                                  int* __restrict__ idx_out) {
  const int wave = threadIdx.x >> 6;
  const int lane = threadIdx.x & 63;
  const int row  = (blockIdx.x << 2) + wave;   // 0..32767
  const int b    = row >> 12;
  const int i    = row & (NPTS - 1);
  const float* xb  = x + (size_t)b * NPTS * F;
  const float* sqb = sq + (b << 12);
  const float sqi  = sqb[i];

  // x_i: wave-uniform loads (compiler scalarizes)
  float xiq[F];
#pragma unroll
  for (int f = 0; f < F; ++f) xiq[f] = xb[(size_t)i * F + f];

  // list entry per lane (<32): key=0xFFFFFFFF empty, lane field identifies slot
  unsigned long long ent = 0xFFFFFFFF00000000ULL | ((unsigned long long)lane << 12);
  unsigned long long M   = 0xFFFFFFFF00000000ULL | (31ULL << 12);   // current max entry

#pragma unroll 1
  for (int c4 = 0; c4 < 16; ++c4) {
    const int j0 = (c4 << 8) + (lane << 2);
    const float4 sq4 = *reinterpret_cast<const float4*>(sqb + j0);
    const float sqj[4] = {sq4.x, sq4.y, sq4.z, sq4.w};
    float dd[4];
#pragma unroll
    for (int s = 0; s < 4; ++s) {
      const float* xj = xb + (size_t)(j0 + s) * F;
      float dot = 0.f;
      if constexpr (F % 4 == 0) {
        const float4* xj4 = reinterpret_cast<const float4*>(xj);
#pragma unroll
        for (int q = 0; q < F / 4; ++q) {
          float4 v = xj4[q];
          dot = fmaf(xiq[4 * q + 0], v.x, dot);
          dot = fmaf(xiq[4 * q + 1], v.y, dot);
          dot = fmaf(xiq[4 * q + 2], v.z, dot);
          dot = fmaf(xiq[4 * q + 3], v.w, dot);
        }
      } else {
#pragma unroll
        for (int f = 0; f < F; ++f) dot = fmaf(xiq[f], xj[f], dot);
      }
      dd[s] = fmaf(-2.f, dot, sqi + sqj[s]);
    }
#pragma unroll
    for (int s = 0; s < 4; ++s) {
      unsigned u  = __float_as_uint(dd[s]);
      unsigned ck = (u & 0x80000000u) ? ~u : (u | 0x80000000u);  // order-preserving key
      unsigned long long mask = __ballot(ck < (unsigned)(M >> 32));
      while (mask) {
        const int src = __builtin_ctzll(mask);
        mask &= mask - 1;
        const unsigned bk = (unsigned)__shfl((int)ck, src, 64);
        if (bk < (unsigned)(M >> 32)) {
          const unsigned bidx  = (unsigned)((c4 << 8) | (src << 2) | s);
          const int      owner = (int)((M >> 12) & 63ULL);
          if (lane == owner)
            ent = ((unsigned long long)bk << 32) | ((unsigned long long)owner << 12) | bidx;
          unsigned long long v = (lane < 32) ? ent : 0ULL;
#pragma unroll
          for (int off = 32; off >= 1; off >>= 1) {
            unsigned long long w = shfl_xor_u64(v, off);
            v = (v > w) ? v : w;
          }
          M = v;
        }
      }
    }
  }
  if (lane < 32)
    idx_out[(row << 5) + lane] = (b << 12) + (int)(ent & 0xFFFULL);
}

// ---------------- per-node P = x.Wbot ; C = x.(Wtop-Wbot) + b ----------------
__global__ __launch_bounds__(256) void mlp_pc_kernel(const float* __restrict__ xin,
                                                     const float* __restrict__ W,
                                                     const float* __restrict__ bias,
                                                     float* __restrict__ P,
                                                     float* C,
                                                     int F, int O, int total) {
  int t = blockIdx.x * 256 + threadIdx.x;
  if (t >= total) return;
  int n = t / O, o = t % O;
  const float* xr = xin + (size_t)n * F;
  const float* Wt = W + o;
  const float* Wb = W + (size_t)F * O + o;
  float p = 0.f, c = 0.f;
  for (int f = 0; f < F; ++f) {
    float a  = xr[f];
    float wt = Wt[(size_t)f * O];
    float wb = Wb[(size_t)f * O];
    p = fmaf(a, wb, p);
    c = fmaf(a, wt - wb, c);
  }
  P[t] = p;
  C[t] = c + bias[o];
}

// ---------------- h[t] (pre-filled with C) += max_k P[idx_k] ----------------
__global__ __launch_bounds__(256) void aggregate_kernel(const int* __restrict__ idx,
                                                        const float* __restrict__ P,
                                                        float* h, int O, int total) {
  int t = blockIdx.x * 256 + threadIdx.x;
  if (t >= total) return;
  int n = t / O, o = t % O;
  const int* ix = idx + (size_t)n * KNN;
  float m = -3.402823466e+38f;
  for (int k = 0; k < KNN; ++k) {
    int jg = ix[k];
    float v = P[(size_t)jg * O + o];
    m = fmaxf(m, v);
  }
  h[t] = h[t] + m;
}

// ---------------- BN stats over relu(h): mean + invstd per channel ----------
__global__ __launch_bounds__(256) void bn_stats_kernel(const float* __restrict__ h,
                                                       float* __restrict__ stats) {
  const int c = blockIdx.x;      // 0..63
  const int t = threadIdx.x;
  double s = 0.0, s2 = 0.0;
  for (int n = t; n < NROWS; n += 256) {
    float v = h[(size_t)n * 64 + c];
    v = v > 0.f ? v : 0.f;
    s += v;
    s2 += (double)v * v;
  }
  __shared__ double ls[256], ls2[256];
  ls[t] = s; ls2[t] = s2;
  __syncthreads();
  for (int st = 128; st; st >>= 1) {
    if (t < st) { ls[t] += ls[t + st]; ls2[t] += ls2[t + st]; }
    __syncthreads();
  }
  if (t == 0) {
    double mean = ls[0] / (double)NROWS;
    double var  = ls2[0] / (double)NROWS - mean * mean;
    stats[c]      = (float)mean;
    stats[64 + c] = (float)(1.0 / sqrt(var + 1e-5));
  }
}

// ---------------- apply: out = (relu(h)-mean)*invstd*g + be  (in-place ok) ---
__global__ __launch_bounds__(256) void bn_apply_kernel(const float* h,
                                                       const float* __restrict__ stats,
                                                       const float* __restrict__ g,
                                                       const float* __restrict__ be,
                                                       float* out, int total) {
  int t = blockIdx.x * 256 + threadIdx.x;
  if (t >= total) return;
  int ch = t & 63;
  float v = fmaxf(h[t], 0.f);
  out[t] = (v - stats[ch]) * stats[64 + ch] * g[ch] + be[ch];
}

// ---------------- write h3 to out + per-block loss partials ----------------
__global__ __launch_bounds__(256) void final_kernel(const float* __restrict__ h3,
                                                    const float* __restrict__ target,
                                                    float* __restrict__ out,
                                                    double* __restrict__ partial) {
  double s = 0.0;
  for (int t = blockIdx.x * 256 + threadIdx.x; t < NROWS * 3; t += 256 * 256) {
    float v = h3[t];
    out[t] = v;
    float d = v - target[t];
    s += (double)d * d;
  }
  __shared__ double ls[256];
  int t = threadIdx.x;
  ls[t] = s;
  __syncthreads();
  for (int st = 128; st; st >>= 1) {
    if (t < st) ls[t] += ls[t + st];
    __syncthreads();
  }
  if (t == 0) partial[blockIdx.x] = ls[0];
}

__global__ __launch_bounds__(256) void loss_kernel(const double* __restrict__ partial,
                                                   float* __restrict__ out) {
  int t = threadIdx.x;
  __shared__ double ls[256];
  ls[t] = partial[t];
  __syncthreads();
  for (int st = 128; st; st >>= 1) {
    if (t < st) ls[t] += ls[t + st];
    __syncthreads();
  }
  if (t == 0) out[NROWS * 3] = (float)(ls[0] / (double)(NROWS * 3));
}

// ---------------- driver ----------------
extern "C" void kernel_launch(void* const* d_in, const int* in_sizes, int n_in,
                              void* d_out, int out_size, void* d_ws, size_t ws_size,
                              hipStream_t stream) {
  const float* x   = (const float*)d_in[0];
  const float* tgt = (const float*)d_in[1];
  const float* W1  = (const float*)d_in[2];
  const float* b1  = (const float*)d_in[3];
  const float* g1  = (const float*)d_in[4];
  const float* be1 = (const float*)d_in[5];
  const float* W2  = (const float*)d_in[6];
  const float* b2  = (const float*)d_in[7];
  const float* g2  = (const float*)d_in[8];
  const float* be2 = (const float*)d_in[9];
  const float* W3  = (const float*)d_in[10];
  const float* b3  = (const float*)d_in[11];
  float* out = (float*)d_out;

  char* ws = (char*)d_ws;
  size_t off = 0;
  float* sq   = (float*)(ws + off); off += (size_t)NROWS * 4;            // 128 KB
  int*   idxb = (int*)(ws + off);   off += (size_t)NROWS * KNN * 4;      // 4 MB
  float* P    = (float*)(ws + off); off += (size_t)NROWS * 64 * 4;       // 8 MB
  float* CA   = (float*)(ws + off); off += (size_t)NROWS * 64 * 4;       // 8 MB
  float* CB   = (float*)(ws + off); off += (size_t)NROWS * 64 * 4;       // 8 MB
  float* stats= (float*)(ws + off); off += 256 * 4;
  double* part= (double*)(ws + off); off += 256 * 8;

  const int T64 = NROWS * 64;          // 2097152
  const int T3  = NROWS * 3;           // 98304

  // ---- layer 1 (F=3 -> 64) ----
  sqnorm_kernel<<<NROWS / 256, 256, 0, stream>>>(x, sq, 3);
  knn_kernel<3><<<NROWS / 4, 256, 0, stream>>>(x, sq, idxb);
  mlp_pc_kernel<<<T64 / 256, 256, 0, stream>>>(x, W1, b1, P, CA, 3, 64, T64);
  aggregate_kernel<<<T64 / 256, 256, 0, stream>>>(idxb, P, CA, 64, T64);
  bn_stats_kernel<<<64, 256, 0, stream>>>(CA, stats);
  bn_apply_kernel<<<T64 / 256, 256, 0, stream>>>(CA, stats, g1, be1, CA, T64);

  // ---- layer 2 (F=64 -> 64) ----
  sqnorm_kernel<<<NROWS / 256, 256, 0, stream>>>(CA, sq, 64);
  knn_kernel<64><<<NROWS / 4, 256, 0, stream>>>(CA, sq, idxb);
  mlp_pc_kernel<<<T64 / 256, 256, 0, stream>>>(CA, W2, b2, P, CB, 64, 64, T64);
  aggregate_kernel<<<T64 / 256, 256, 0, stream>>>(idxb, P, CB, 64, T64);
  bn_stats_kernel<<<64, 256, 0, stream>>>(CB, stats);
  bn_apply_kernel<<<T64 / 256, 256, 0, stream>>>(CB, stats, g2, be2, CB, T64);

  // ---- layer 3 (F=64 -> 3, no relu/bn) ----
  sqnorm_kernel<<<NROWS / 256, 256, 0, stream>>>(CB, sq, 64);
  knn_kernel<64><<<NROWS / 4, 256, 0, stream>>>(CB, sq, idxb);
  mlp_pc_kernel<<<T3 / 256, 256, 0, stream>>>(CB, W3, b3, P, CA, 64, 3, T3);
  aggregate_kernel<<<T3 / 256, 256, 0, stream>>>(idxb, P, CA, 3, T3);

  // ---- output + loss ----
  final_kernel<<<256, 256, 0, stream>>>(CA, tgt, out, part);
  loss_kernel<<<1, 256, 0, stream>>>(part, out);
}

// Round 3
// 3458.117 us; speedup vs baseline: 3.2350x; 3.2350x over previous
//
#include <hip/hip_runtime.h>
#include <cstdint>
#include <cstddef>

static constexpr int NPTS  = 4096;
static constexpr int NB    = 8;
static constexpr int NROWS = NB * NPTS;      // 32768
static constexpr int KNN   = 32;

// ---------------- utility: 64-bit shfl_xor built from 32-bit ----------------
__device__ __forceinline__ unsigned long long shfl_xor_u64(unsigned long long v, int m) {
  int lo = __shfl_xor((int)(unsigned)(v & 0xFFFFFFFFULL), m, 64);
  int hi = __shfl_xor((int)(unsigned)(v >> 32), m, 64);
  return ((unsigned long long)(unsigned)hi << 32) | (unsigned)lo;
}

// ---------------- squared norms per point ----------------
__global__ __launch_bounds__(256) void sqnorm_kernel(const float* __restrict__ x,
                                                     float* __restrict__ sq, int F) {
  int t = blockIdx.x * 256 + threadIdx.x;
  if (t >= NROWS) return;
  const float* p = x + (size_t)t * F;
  float s = 0.f;
  for (int f = 0; f < F; ++f) s = fmaf(p[f], p[f], s);
  sq[t] = s;
}

// ---------------- tiled fused dist + top-32 selection ----------------
// Block = 256 threads (4 waves) owns 16 query rows (4 per wave). Candidate
// tiles of 128 staged in LDS. Each lane owns 2 candidates (lane, lane+64).
// Top-32 per row: distributed list, one slot per lane&31, mirrored across
// both 32-lane halves (5-step shfl_xor max-reduce).
// Entry packing: ((key<<12)|idx) << 5 | slot  — eviction compares entry>>5,
// a unique lexicographic (dist,idx) order => kept set is EXACTLY the 32
// smallest (dist,idx), independent of insertion order, matching stable
// jax.lax.top_k tie semantics.
template <int F>
__global__ __launch_bounds__(256, 4) void knn_tiled(const float* __restrict__ x,
                                                    const float* __restrict__ sq,
                                                    int* __restrict__ idx_out) {
  constexpr int FP = (F == 3) ? 4 : (F + 4);   // padded LDS row stride (floats)
  constexpr int TC = 128;                      // candidates per tile

  __shared__ __attribute__((aligned(16))) float qv[16][FP];
  __shared__ float qsq[16];
  __shared__ __attribute__((aligned(16))) float ct[TC][FP];
  __shared__ float csq[TC];

  const int t    = threadIdx.x;
  const int wave = t >> 6;
  const int lane = t & 63;
  const int rowbase = blockIdx.x << 4;         // 16 rows per block
  const int b     = rowbase >> 12;
  const int ibase = rowbase & (NPTS - 1);
  const float* xb  = x + (size_t)b * NPTS * F;
  const float* sqb = sq + (b << 12);

  // ---- stage the 16 query rows ----
  if constexpr (F == 64) {
    int r = t >> 4, ch = t & 15;
    float4 v = *reinterpret_cast<const float4*>(xb + (size_t)(ibase + r) * 64 + ch * 4);
    *reinterpret_cast<float4*>(&qv[r][ch * 4]) = v;
  } else {
    if (t < 16) {
      qv[t][0] = xb[(size_t)(ibase + t) * 3 + 0];
      qv[t][1] = xb[(size_t)(ibase + t) * 3 + 1];
      qv[t][2] = xb[(size_t)(ibase + t) * 3 + 2];
      qv[t][3] = 0.f;
    }
  }
  if (t < 16) qsq[t] = sqb[ibase + t];
  __syncthreads();

  const int r0 = wave << 2;                    // first of this wave's 4 rows
  float sqi[4];
#pragma unroll
  for (int rr = 0; rr < 4; ++rr) sqi[rr] = qsq[r0 + rr];

  // ---- distributed top-32 state (mirrored halves) ----
  // empty: key=0xFFFFFFFF, idx=0xFFF
  unsigned long long ent[4], M[4];
#pragma unroll
  for (int rr = 0; rr < 4; ++rr) {
    ent[rr] = (0xFFFFFFFFFFFULL << 5) | (unsigned long long)(lane & 31);
    M[rr]   = (0xFFFFFFFFFFFULL << 5) | 31ULL;
  }

  for (int tile = 0; tile < NPTS / TC; ++tile) {
    __syncthreads();
    // ---- stage candidate tile ----
    if constexpr (F == 64) {
#pragma unroll
      for (int k = 0; k < 8; ++k) {
        int idx = t + k * 256;
        int c = idx >> 4, ch = idx & 15;
        float4 v = *reinterpret_cast<const float4*>(
            xb + (size_t)(tile * TC + c) * 64 + ch * 4);
        *reinterpret_cast<float4*>(&ct[c][ch * 4]) = v;
      }
      if (t < TC) csq[t] = sqb[tile * TC + t];
    } else {
      if (t < TC) {
        int jg = tile * TC + t;
        ct[t][0] = xb[(size_t)jg * 3 + 0];
        ct[t][1] = xb[(size_t)jg * 3 + 1];
        ct[t][2] = xb[(size_t)jg * 3 + 2];
        ct[t][3] = 0.f;
        csq[t] = sqb[jg];
      }
    }
    __syncthreads();

    // ---- distances: 4 rows x 2 cands per lane (ascending-f fma chain,
    //      bit-identical to the validated R1 ordering) ----
    float dot[4][2] = {{0.f, 0.f}, {0.f, 0.f}, {0.f, 0.f}, {0.f, 0.f}};
    if constexpr (F == 64) {
#pragma unroll 4
      for (int ch = 0; ch < 16; ++ch) {
        float4 c0 = *reinterpret_cast<const float4*>(&ct[lane][ch * 4]);
        float4 c1 = *reinterpret_cast<const float4*>(&ct[lane + 64][ch * 4]);
#pragma unroll
        for (int rr = 0; rr < 4; ++rr) {
          float4 q = *reinterpret_cast<const float4*>(&qv[r0 + rr][ch * 4]);
          dot[rr][0] = fmaf(q.x, c0.x, dot[rr][0]);
          dot[rr][0] = fmaf(q.y, c0.y, dot[rr][0]);
          dot[rr][0] = fmaf(q.z, c0.z, dot[rr][0]);
          dot[rr][0] = fmaf(q.w, c0.w, dot[rr][0]);
          dot[rr][1] = fmaf(q.x, c1.x, dot[rr][1]);
          dot[rr][1] = fmaf(q.y, c1.y, dot[rr][1]);
          dot[rr][1] = fmaf(q.z, c1.z, dot[rr][1]);
          dot[rr][1] = fmaf(q.w, c1.w, dot[rr][1]);
        }
      }
    } else {
      float4 c0 = *reinterpret_cast<const float4*>(&ct[lane][0]);
      float4 c1 = *reinterpret_cast<const float4*>(&ct[lane + 64][0]);
#pragma unroll
      for (int rr = 0; rr < 4; ++rr) {
        float4 q = *reinterpret_cast<const float4*>(&qv[r0 + rr][0]);
        dot[rr][0] = fmaf(q.z, c0.z, fmaf(q.y, c0.y, q.x * c0.x));
        dot[rr][1] = fmaf(q.z, c1.z, fmaf(q.y, c1.y, q.x * c1.x));
      }
    }

    const float cs0 = csq[lane];
    const float cs1 = csq[lane + 64];

    // ---- selection ----
#pragma unroll
    for (int rr = 0; rr < 4; ++rr) {
#pragma unroll
      for (int s = 0; s < 2; ++s) {
        float d = fmaf(-2.f, dot[rr][s], sqi[rr] + (s == 0 ? cs0 : cs1));
        unsigned u  = __float_as_uint(d);
        unsigned ck = (u & 0x80000000u) ? ~u : (u | 0x80000000u);
        const unsigned cidx = (unsigned)(tile * TC + s * 64 + lane);
        const unsigned long long cq =
            ((unsigned long long)ck << 12) | cidx;          // 44-bit (dist,idx)
        unsigned long long mask = __ballot(cq < (M[rr] >> 5));
        while (mask) {
          const int src = __builtin_ctzll(mask);
          mask &= mask - 1;
          const unsigned bk   = (unsigned)__shfl((int)ck, src, 64);
          const unsigned bidx = (unsigned)(tile * TC + s * 64 + src);
          const unsigned long long bq = ((unsigned long long)bk << 12) | bidx;
          if (bq < (M[rr] >> 5)) {
            const unsigned slot = (unsigned)(M[rr] & 31ULL);
            if ((unsigned)(lane & 31) == slot)
              ent[rr] = (bq << 5) | slot;
            unsigned long long v = ent[rr];
#pragma unroll
            for (int off = 16; off >= 1; off >>= 1) {
              unsigned long long w2 = shfl_xor_u64(v, off);
              v = (v > w2) ? v : w2;
            }
            M[rr] = v;
          }
        }
      }
    }
  }

  if (lane < 32) {
#pragma unroll
    for (int rr = 0; rr < 4; ++rr)
      idx_out[((rowbase + r0 + rr) << 5) + lane] =
          (b << 12) + (int)((ent[rr] >> 5) & 0xFFFULL);
  }
}

// ---------------- per-node P = x.Wbot ; C = x.(Wtop-Wbot) + b ----------------
__global__ __launch_bounds__(256) void mlp_pc_kernel(const float* __restrict__ xin,
                                                     const float* __restrict__ W,
                                                     const float* __restrict__ bias,
                                                     float* __restrict__ P,
                                                     float* C,
                                                     int F, int O, int total) {
  int t = blockIdx.x * 256 + threadIdx.x;
  if (t >= total) return;
  int n = t / O, o = t % O;
  const float* xr = xin + (size_t)n * F;
  const float* Wt = W + o;
  const float* Wb = W + (size_t)F * O + o;
  float p = 0.f, c = 0.f;
  for (int f = 0; f < F; ++f) {
    float a  = xr[f];
    float wt = Wt[(size_t)f * O];
    float wb = Wb[(size_t)f * O];
    p = fmaf(a, wb, p);
    c = fmaf(a, wt - wb, c);
  }
  P[t] = p;
  C[t] = c + bias[o];
}

// ---------------- h[t] (pre-filled with C) += max_k P[idx_k] ----------------
__global__ __launch_bounds__(256) void aggregate_kernel(const int* __restrict__ idx,
                                                        const float* __restrict__ P,
                                                        float* h, int O, int total) {
  int t = blockIdx.x * 256 + threadIdx.x;
  if (t >= total) return;
  int n = t / O, o = t % O;
  const int* ix = idx + (size_t)n * KNN;
  float m = -3.402823466e+38f;
  for (int k = 0; k < KNN; ++k) {
    int jg = ix[k];
    float v = P[(size_t)jg * O + o];
    m = fmaxf(m, v);
  }
  h[t] = h[t] + m;
}

// ---------------- BN stats over relu(h): mean + invstd per channel ----------
__global__ __launch_bounds__(256) void bn_stats_kernel(const float* __restrict__ h,
                                                       float* __restrict__ stats) {
  const int c = blockIdx.x;      // 0..63
  const int t = threadIdx.x;
  double s = 0.0, s2 = 0.0;
  for (int n = t; n < NROWS; n += 256) {
    float v = h[(size_t)n * 64 + c];
    v = v > 0.f ? v : 0.f;
    s += v;
    s2 += (double)v * v;
  }
  __shared__ double ls[256], ls2[256];
  ls[t] = s; ls2[t] = s2;
  __syncthreads();
  for (int st = 128; st; st >>= 1) {
    if (t < st) { ls[t] += ls[t + st]; ls2[t] += ls2[t + st]; }
    __syncthreads();
  }
  if (t == 0) {
    double mean = ls[0] / (double)NROWS;
    double var  = ls2[0] / (double)NROWS - mean * mean;
    stats[c]      = (float)mean;
    stats[64 + c] = (float)(1.0 / sqrt(var + 1e-5));
  }
}

// ---------------- apply: out = (relu(h)-mean)*invstd*g + be  (in-place ok) ---
__global__ __launch_bounds__(256) void bn_apply_kernel(const float* h,
                                                       const float* __restrict__ stats,
                                                       const float* __restrict__ g,
                                                       const float* __restrict__ be,
                                                       float* out, int total) {
  int t = blockIdx.x * 256 + threadIdx.x;
  if (t >= total) return;
  int ch = t & 63;
  float v = fmaxf(h[t], 0.f);
  out[t] = (v - stats[ch]) * stats[64 + ch] * g[ch] + be[ch];
}

// ---------------- write h3 to out + per-block loss partials ----------------
__global__ __launch_bounds__(256) void final_kernel(const float* __restrict__ h3,
                                                    const float* __restrict__ target,
                                                    float* __restrict__ out,
                                                    double* __restrict__ partial) {
  double s = 0.0;
  for (int t = blockIdx.x * 256 + threadIdx.x; t < NROWS * 3; t += 256 * 256) {
    float v = h3[t];
    out[t] = v;
    float d = v - target[t];
    s += (double)d * d;
  }
  __shared__ double ls[256];
  int t = threadIdx.x;
  ls[t] = s;
  __syncthreads();
  for (int st = 128; st; st >>= 1) {
    if (t < st) ls[t] += ls[t + st];
    __syncthreads();
  }
  if (t == 0) partial[blockIdx.x] = ls[0];
}

__global__ __launch_bounds__(256) void loss_kernel(const double* __restrict__ partial,
                                                   float* __restrict__ out) {
  int t = threadIdx.x;
  __shared__ double ls[256];
  ls[t] = partial[t];
  __syncthreads();
  for (int st = 128; st; st >>= 1) {
    if (t < st) ls[t] += ls[t + st];
    __syncthreads();
  }
  if (t == 0) out[NROWS * 3] = (float)(ls[0] / (double)(NROWS * 3));
}

// ---------------- driver ----------------
extern "C" void kernel_launch(void* const* d_in, const int* in_sizes, int n_in,
                              void* d_out, int out_size, void* d_ws, size_t ws_size,
                              hipStream_t stream) {
  const float* x   = (const float*)d_in[0];
  const float* tgt = (const float*)d_in[1];
  const float* W1  = (const float*)d_in[2];
  const float* b1  = (const float*)d_in[3];
  const float* g1  = (const float*)d_in[4];
  const float* be1 = (const float*)d_in[5];
  const float* W2  = (const float*)d_in[6];
  const float* b2  = (const float*)d_in[7];
  const float* g2  = (const float*)d_in[8];
  const float* be2 = (const float*)d_in[9];
  const float* W3  = (const float*)d_in[10];
  const float* b3  = (const float*)d_in[11];
  float* out = (float*)d_out;

  char* ws = (char*)d_ws;
  size_t off = 0;
  float* sq   = (float*)(ws + off); off += (size_t)NROWS * 4;            // 128 KB
  int*   idxb = (int*)(ws + off);   off += (size_t)NROWS * KNN * 4;      // 4 MB
  float* P    = (float*)(ws + off); off += (size_t)NROWS * 64 * 4;       // 8 MB
  float* CA   = (float*)(ws + off); off += (size_t)NROWS * 64 * 4;       // 8 MB
  float* CB   = (float*)(ws + off); off += (size_t)NROWS * 64 * 4;       // 8 MB
  float* stats= (float*)(ws + off); off += 256 * 4;
  double* part= (double*)(ws + off); off += 256 * 8;

  const int T64 = NROWS * 64;          // 2097152
  const int T3  = NROWS * 3;           // 98304
  const int KNN_GRID = NROWS / 16;     // 2048 blocks

  // ---- layer 1 (F=3 -> 64) ----
  sqnorm_kernel<<<NROWS / 256, 256, 0, stream>>>(x, sq, 3);
  knn_tiled<3><<<KNN_GRID, 256, 0, stream>>>(x, sq, idxb);
  mlp_pc_kernel<<<T64 / 256, 256, 0, stream>>>(x, W1, b1, P, CA, 3, 64, T64);
  aggregate_kernel<<<T64 / 256, 256, 0, stream>>>(idxb, P, CA, 64, T64);
  bn_stats_kernel<<<64, 256, 0, stream>>>(CA, stats);
  bn_apply_kernel<<<T64 / 256, 256, 0, stream>>>(CA, stats, g1, be1, CA, T64);

  // ---- layer 2 (F=64 -> 64) ----
  sqnorm_kernel<<<NROWS / 256, 256, 0, stream>>>(CA, sq, 64);
  knn_tiled<64><<<KNN_GRID, 256, 0, stream>>>(CA, sq, idxb);
  mlp_pc_kernel<<<T64 / 256, 256, 0, stream>>>(CA, W2, b2, P, CB, 64, 64, T64);
  aggregate_kernel<<<T64 / 256, 256, 0, stream>>>(idxb, P, CB, 64, T64);
  bn_stats_kernel<<<64, 256, 0, stream>>>(CB, stats);
  bn_apply_kernel<<<T64 / 256, 256, 0, stream>>>(CB, stats, g2, be2, CB, T64);

  // ---- layer 3 (F=64 -> 3, no relu/bn) ----
  sqnorm_kernel<<<NROWS / 256, 256, 0, stream>>>(CB, sq, 64);
  knn_tiled<64><<<KNN_GRID, 256, 0, stream>>>(CB, sq, idxb);
  mlp_pc_kernel<<<T3 / 256, 256, 0, stream>>>(CB, W3, b3, P, CA, 64, 3, T3);
  aggregate_kernel<<<T3 / 256, 256, 0, stream>>>(idxb, P, CA, 3, T3);

  // ---- output + loss ----
  final_kernel<<<256, 256, 0, stream>>>(CA, tgt, out, part);
  loss_kernel<<<1, 256, 0, stream>>>(part, out);
}

// Round 4
// 2452.378 us; speedup vs baseline: 4.5617x; 1.4101x over previous
//
#include <hip/hip_runtime.h>
#include <cstdint>
#include <cstddef>

static constexpr int NPTS  = 4096;
static constexpr int NB    = 8;
static constexpr int NROWS = NB * NPTS;      // 32768
static constexpr int KNN   = 32;

// ---------------- utility: 64-bit shfl_xor built from 32-bit ----------------
__device__ __forceinline__ unsigned long long shfl_xor_u64(unsigned long long v, int m) {
  int lo = __shfl_xor((int)(unsigned)(v & 0xFFFFFFFFULL), m, 64);
  int hi = __shfl_xor((int)(unsigned)(v >> 32), m, 64);
  return ((unsigned long long)(unsigned)hi << 32) | (unsigned)lo;
}

// ---------------- squared norms per point ----------------
__global__ __launch_bounds__(256) void sqnorm_kernel(const float* __restrict__ x,
                                                     float* __restrict__ sq, int F) {
  int t = blockIdx.x * 256 + threadIdx.x;
  if (t >= NROWS) return;
  const float* p = x + (size_t)t * F;
  float s = 0.f;
  for (int f = 0; f < F; ++f) s = fmaf(p[f], p[f], s);
  sq[t] = s;
}

// ---------------- two-pass tiled kNN: prefilter + exact select ----------------
// Block = 256 threads (4 waves) owns 16 query rows (4 per wave). Candidate
// tiles of 128 staged in LDS; lane owns 2 candidates (lane, lane+64).
//
// Pass A: stream tiles, compute order-keys, track per-(row,lane) local min.
// tau0[row] = exact 32nd-smallest of the 64 lane minima (wave radix-select).
// Since the 32 smallest lane-minima are 32 distinct candidates with key<=tau0,
// the true 32nd-smallest key* <= tau0 -> filtering by key<=tau0 keeps a
// superset of the lex-(key,idx) top-32.
// Pass B: re-stream tiles (bit-identical fma chain -> identical keys), run the
// validated exact ballot-insert only on candidates with key<=tau0 (~44/row).
// Entry packing ((key<<12)|idx)<<5|slot; eviction on entry>>5 = lex (dist,idx),
// insertion-order independent, matches stable jax.lax.top_k tie semantics.
template <int F>
__global__ __launch_bounds__(256, 4) void knn_tiled(const float* __restrict__ x,
                                                    const float* __restrict__ sq,
                                                    int* __restrict__ idx_out) {
  constexpr int FP = (F == 3) ? 4 : (F + 4);   // padded LDS row stride (floats)
  constexpr int TC = 128;                      // candidates per tile

  __shared__ __attribute__((aligned(16))) float qv[16][FP];
  __shared__ float qsq[16];
  __shared__ __attribute__((aligned(16))) float ct[TC][FP];
  __shared__ float csq[TC];

  const int t    = threadIdx.x;
  const int wave = t >> 6;
  const int lane = t & 63;
  const int rowbase = blockIdx.x << 4;         // 16 rows per block
  const int b     = rowbase >> 12;
  const int ibase = rowbase & (NPTS - 1);
  const float* xb  = x + (size_t)b * NPTS * F;
  const float* sqb = sq + (b << 12);

  // ---- stage the 16 query rows (persist across both passes) ----
  if constexpr (F == 64) {
    int r = t >> 4, ch = t & 15;
    float4 v = *reinterpret_cast<const float4*>(xb + (size_t)(ibase + r) * 64 + ch * 4);
    *reinterpret_cast<float4*>(&qv[r][ch * 4]) = v;
  } else {
    if (t < 16) {
      qv[t][0] = xb[(size_t)(ibase + t) * 3 + 0];
      qv[t][1] = xb[(size_t)(ibase + t) * 3 + 1];
      qv[t][2] = xb[(size_t)(ibase + t) * 3 + 2];
      qv[t][3] = 0.f;
    }
  }
  if (t < 16) qsq[t] = sqb[ibase + t];
  __syncthreads();

  const int r0 = wave << 2;                    // first of this wave's 4 rows
  float sqi[4];
#pragma unroll
  for (int rr = 0; rr < 4; ++rr) sqi[rr] = qsq[r0 + rr];

  // ================= PASS A: local minima =================
  unsigned mn[4] = {0xFFFFFFFFu, 0xFFFFFFFFu, 0xFFFFFFFFu, 0xFFFFFFFFu};

  for (int tile = 0; tile < NPTS / TC; ++tile) {
    __syncthreads();
    if constexpr (F == 64) {
#pragma unroll
      for (int k = 0; k < 8; ++k) {
        int idx = t + k * 256;
        int c = idx >> 4, ch = idx & 15;
        float4 v = *reinterpret_cast<const float4*>(
            xb + (size_t)(tile * TC + c) * 64 + ch * 4);
        *reinterpret_cast<float4*>(&ct[c][ch * 4]) = v;
      }
      if (t < TC) csq[t] = sqb[tile * TC + t];
    } else {
      if (t < TC) {
        int jg = tile * TC + t;
        ct[t][0] = xb[(size_t)jg * 3 + 0];
        ct[t][1] = xb[(size_t)jg * 3 + 1];
        ct[t][2] = xb[(size_t)jg * 3 + 2];
        ct[t][3] = 0.f;
        csq[t] = sqb[jg];
      }
    }
    __syncthreads();

    float dot[4][2] = {{0.f, 0.f}, {0.f, 0.f}, {0.f, 0.f}, {0.f, 0.f}};
    if constexpr (F == 64) {
#pragma unroll 4
      for (int ch = 0; ch < 16; ++ch) {
        float4 c0 = *reinterpret_cast<const float4*>(&ct[lane][ch * 4]);
        float4 c1 = *reinterpret_cast<const float4*>(&ct[lane + 64][ch * 4]);
#pragma unroll
        for (int rr = 0; rr < 4; ++rr) {
          float4 q = *reinterpret_cast<const float4*>(&qv[r0 + rr][ch * 4]);
          dot[rr][0] = fmaf(q.x, c0.x, dot[rr][0]);
          dot[rr][0] = fmaf(q.y, c0.y, dot[rr][0]);
          dot[rr][0] = fmaf(q.z, c0.z, dot[rr][0]);
          dot[rr][0] = fmaf(q.w, c0.w, dot[rr][0]);
          dot[rr][1] = fmaf(q.x, c1.x, dot[rr][1]);
          dot[rr][1] = fmaf(q.y, c1.y, dot[rr][1]);
          dot[rr][1] = fmaf(q.z, c1.z, dot[rr][1]);
          dot[rr][1] = fmaf(q.w, c1.w, dot[rr][1]);
        }
      }
    } else {
      float4 c0 = *reinterpret_cast<const float4*>(&ct[lane][0]);
      float4 c1 = *reinterpret_cast<const float4*>(&ct[lane + 64][0]);
#pragma unroll
      for (int rr = 0; rr < 4; ++rr) {
        float4 q = *reinterpret_cast<const float4*>(&qv[r0 + rr][0]);
        dot[rr][0] = fmaf(q.z, c0.z, fmaf(q.y, c0.y, q.x * c0.x));
        dot[rr][1] = fmaf(q.z, c1.z, fmaf(q.y, c1.y, q.x * c1.x));
      }
    }

    const float cs0 = csq[lane];
    const float cs1 = csq[lane + 64];
#pragma unroll
    for (int rr = 0; rr < 4; ++rr) {
#pragma unroll
      for (int s = 0; s < 2; ++s) {
        float d = fmaf(-2.f, dot[rr][s], sqi[rr] + (s == 0 ? cs0 : cs1));
        unsigned u  = __float_as_uint(d);
        unsigned ck = (u & 0x80000000u) ? ~u : (u | 0x80000000u);
        mn[rr] = ck < mn[rr] ? ck : mn[rr];
      }
    }
  }

  // ---- tau0[row]: exact 32nd-smallest of the 64 lane minima ----
  unsigned tau[4];
#pragma unroll
  for (int rr = 0; rr < 4; ++rr) {
    const unsigned v = mn[rr];
    unsigned prefix = 0;
    int need = 32;
    int act = 1;
    for (int bit = 31; bit >= 0; --bit) {
      const unsigned bv = (v >> bit) & 1u;
      unsigned long long m0 = __ballot(act && (bv == 0u));
      int c0 = (int)__popcll(m0);
      if (c0 >= need) {
        act = act && (bv == 0u);
      } else {
        need -= c0;
        act = act && (bv == 1u);
        prefix |= (1u << bit);
      }
    }
    tau[rr] = prefix;
  }

  // ================= PASS B: exact select over prefiltered =================
  unsigned long long ent[4], M[4];
#pragma unroll
  for (int rr = 0; rr < 4; ++rr) {
    ent[rr] = (0xFFFFFFFFFFFULL << 5) | (unsigned long long)(lane & 31);
    M[rr]   = (0xFFFFFFFFFFFULL << 5) | 31ULL;
  }

  for (int tile = 0; tile < NPTS / TC; ++tile) {
    __syncthreads();
    if constexpr (F == 64) {
#pragma unroll
      for (int k = 0; k < 8; ++k) {
        int idx = t + k * 256;
        int c = idx >> 4, ch = idx & 15;
        float4 v = *reinterpret_cast<const float4*>(
            xb + (size_t)(tile * TC + c) * 64 + ch * 4);
        *reinterpret_cast<float4*>(&ct[c][ch * 4]) = v;
      }
      if (t < TC) csq[t] = sqb[tile * TC + t];
    } else {
      if (t < TC) {
        int jg = tile * TC + t;
        ct[t][0] = xb[(size_t)jg * 3 + 0];
        ct[t][1] = xb[(size_t)jg * 3 + 1];
        ct[t][2] = xb[(size_t)jg * 3 + 2];
        ct[t][3] = 0.f;
        csq[t] = sqb[jg];
      }
    }
    __syncthreads();

    float dot[4][2] = {{0.f, 0.f}, {0.f, 0.f}, {0.f, 0.f}, {0.f, 0.f}};
    if constexpr (F == 64) {
#pragma unroll 4
      for (int ch = 0; ch < 16; ++ch) {
        float4 c0 = *reinterpret_cast<const float4*>(&ct[lane][ch * 4]);
        float4 c1 = *reinterpret_cast<const float4*>(&ct[lane + 64][ch * 4]);
#pragma unroll
        for (int rr = 0; rr < 4; ++rr) {
          float4 q = *reinterpret_cast<const float4*>(&qv[r0 + rr][ch * 4]);
          dot[rr][0] = fmaf(q.x, c0.x, dot[rr][0]);
          dot[rr][0] = fmaf(q.y, c0.y, dot[rr][0]);
          dot[rr][0] = fmaf(q.z, c0.z, dot[rr][0]);
          dot[rr][0] = fmaf(q.w, c0.w, dot[rr][0]);
          dot[rr][1] = fmaf(q.x, c1.x, dot[rr][1]);
          dot[rr][1] = fmaf(q.y, c1.y, dot[rr][1]);
          dot[rr][1] = fmaf(q.z, c1.z, dot[rr][1]);
          dot[rr][1] = fmaf(q.w, c1.w, dot[rr][1]);
        }
      }
    } else {
      float4 c0 = *reinterpret_cast<const float4*>(&ct[lane][0]);
      float4 c1 = *reinterpret_cast<const float4*>(&ct[lane + 64][0]);
#pragma unroll
      for (int rr = 0; rr < 4; ++rr) {
        float4 q = *reinterpret_cast<const float4*>(&qv[r0 + rr][0]);
        dot[rr][0] = fmaf(q.z, c0.z, fmaf(q.y, c0.y, q.x * c0.x));
        dot[rr][1] = fmaf(q.z, c1.z, fmaf(q.y, c1.y, q.x * c1.x));
      }
    }

    const float cs0 = csq[lane];
    const float cs1 = csq[lane + 64];

#pragma unroll
    for (int rr = 0; rr < 4; ++rr) {
#pragma unroll
      for (int s = 0; s < 2; ++s) {
        float d = fmaf(-2.f, dot[rr][s], sqi[rr] + (s == 0 ? cs0 : cs1));
        unsigned u  = __float_as_uint(d);
        unsigned ck = (u & 0x80000000u) ? ~u : (u | 0x80000000u);
        unsigned long long mask = __ballot(ck <= tau[rr]);
        while (mask) {
          const int src = __builtin_ctzll(mask);
          mask &= mask - 1;
          const unsigned bk   = (unsigned)__shfl((int)ck, src, 64);
          const unsigned bidx = (unsigned)(tile * TC + s * 64 + src);
          const unsigned long long bq = ((unsigned long long)bk << 12) | bidx;
          if (bq < (M[rr] >> 5)) {
            const unsigned slot = (unsigned)(M[rr] & 31ULL);
            if ((unsigned)(lane & 31) == slot)
              ent[rr] = (bq << 5) | slot;
            unsigned long long v = ent[rr];
#pragma unroll
            for (int off = 16; off >= 1; off >>= 1) {
              unsigned long long w2 = shfl_xor_u64(v, off);
              v = (v > w2) ? v : w2;
            }
            M[rr] = v;
          }
        }
      }
    }
  }

  if (lane < 32) {
#pragma unroll
    for (int rr = 0; rr < 4; ++rr)
      idx_out[((rowbase + r0 + rr) << 5) + lane] =
          (b << 12) + (int)((ent[rr] >> 5) & 0xFFFULL);
  }
}

// ---------------- per-node P = x.Wbot ; C = x.(Wtop-Wbot) + b ----------------
__global__ __launch_bounds__(256) void mlp_pc_kernel(const float* __restrict__ xin,
                                                     const float* __restrict__ W,
                                                     const float* __restrict__ bias,
                                                     float* __restrict__ P,
                                                     float* C,
                                                     int F, int O, int total) {
  int t = blockIdx.x * 256 + threadIdx.x;
  if (t >= total) return;
  int n = t / O, o = t % O;
  const float* xr = xin + (size_t)n * F;
  const float* Wt = W + o;
  const float* Wb = W + (size_t)F * O + o;
  float p = 0.f, c = 0.f;
  for (int f = 0; f < F; ++f) {
    float a  = xr[f];
    float wt = Wt[(size_t)f * O];
    float wb = Wb[(size_t)f * O];
    p = fmaf(a, wb, p);
    c = fmaf(a, wt - wb, c);
  }
  P[t] = p;
  C[t] = c + bias[o];
}

// ---------------- h[t] (pre-filled with C) += max_k P[idx_k] ----------------
__global__ __launch_bounds__(256) void aggregate_kernel(const int* __restrict__ idx,
                                                        const float* __restrict__ P,
                                                        float* h, int O, int total) {
  int t = blockIdx.x * 256 + threadIdx.x;
  if (t >= total) return;
  int n = t / O, o = t % O;
  const int* ix = idx + (size_t)n * KNN;
  float m = -3.402823466e+38f;
  for (int k = 0; k < KNN; ++k) {
    int jg = ix[k];
    float v = P[(size_t)jg * O + o];
    m = fmaxf(m, v);
  }
  h[t] = h[t] + m;
}

// ---------------- BN stats over relu(h): mean + invstd per channel ----------
__global__ __launch_bounds__(256) void bn_stats_kernel(const float* __restrict__ h,
                                                       float* __restrict__ stats) {
  const int c = blockIdx.x;      // 0..63
  const int t = threadIdx.x;
  double s = 0.0, s2 = 0.0;
  for (int n = t; n < NROWS; n += 256) {
    float v = h[(size_t)n * 64 + c];
    v = v > 0.f ? v : 0.f;
    s += v;
    s2 += (double)v * v;
  }
  __shared__ double ls[256], ls2[256];
  ls[t] = s; ls2[t] = s2;
  __syncthreads();
  for (int st = 128; st; st >>= 1) {
    if (t < st) { ls[t] += ls[t + st]; ls2[t] += ls2[t + st]; }
    __syncthreads();
  }
  if (t == 0) {
    double mean = ls[0] / (double)NROWS;
    double var  = ls2[0] / (double)NROWS - mean * mean;
    stats[c]      = (float)mean;
    stats[64 + c] = (float)(1.0 / sqrt(var + 1e-5));
  }
}

// ---------------- apply: out = (relu(h)-mean)*invstd*g + be  (in-place ok) ---
__global__ __launch_bounds__(256) void bn_apply_kernel(const float* h,
                                                       const float* __restrict__ stats,
                                                       const float* __restrict__ g,
                                                       const float* __restrict__ be,
                                                       float* out, int total) {
  int t = blockIdx.x * 256 + threadIdx.x;
  if (t >= total) return;
  int ch = t & 63;
  float v = fmaxf(h[t], 0.f);
  out[t] = (v - stats[ch]) * stats[64 + ch] * g[ch] + be[ch];
}

// ---------------- write h3 to out + per-block loss partials ----------------
__global__ __launch_bounds__(256) void final_kernel(const float* __restrict__ h3,
                                                    const float* __restrict__ target,
                                                    float* __restrict__ out,
                                                    double* __restrict__ partial) {
  double s = 0.0;
  for (int t = blockIdx.x * 256 + threadIdx.x; t < NROWS * 3; t += 256 * 256) {
    float v = h3[t];
    out[t] = v;
    float d = v - target[t];
    s += (double)d * d;
  }
  __shared__ double ls[256];
  int t = threadIdx.x;
  ls[t] = s;
  __syncthreads();
  for (int st = 128; st; st >>= 1) {
    if (t < st) ls[t] += ls[t + st];
    __syncthreads();
  }
  if (t == 0) partial[blockIdx.x] = ls[0];
}

__global__ __launch_bounds__(256) void loss_kernel(const double* __restrict__ partial,
                                                   float* __restrict__ out) {
  int t = threadIdx.x;
  __shared__ double ls[256];
  ls[t] = partial[t];
  __syncthreads();
  for (int st = 128; st; st >>= 1) {
    if (t < st) ls[t] += ls[t + st];
    __syncthreads();
  }
  if (t == 0) out[NROWS * 3] = (float)(ls[0] / (double)(NROWS * 3));
}

// ---------------- driver ----------------
extern "C" void kernel_launch(void* const* d_in, const int* in_sizes, int n_in,
                              void* d_out, int out_size, void* d_ws, size_t ws_size,
                              hipStream_t stream) {
  const float* x   = (const float*)d_in[0];
  const float* tgt = (const float*)d_in[1];
  const float* W1  = (const float*)d_in[2];
  const float* b1  = (const float*)d_in[3];
  const float* g1  = (const float*)d_in[4];
  const float* be1 = (const float*)d_in[5];
  const float* W2  = (const float*)d_in[6];
  const float* b2  = (const float*)d_in[7];
  const float* g2  = (const float*)d_in[8];
  const float* be2 = (const float*)d_in[9];
  const float* W3  = (const float*)d_in[10];
  const float* b3  = (const float*)d_in[11];
  float* out = (float*)d_out;

  char* ws = (char*)d_ws;
  size_t off = 0;
  float* sq   = (float*)(ws + off); off += (size_t)NROWS * 4;            // 128 KB
  int*   idxb = (int*)(ws + off);   off += (size_t)NROWS * KNN * 4;      // 4 MB
  float* P    = (float*)(ws + off); off += (size_t)NROWS * 64 * 4;       // 8 MB
  float* CA   = (float*)(ws + off); off += (size_t)NROWS * 64 * 4;       // 8 MB
  float* CB   = (float*)(ws + off); off += (size_t)NROWS * 64 * 4;       // 8 MB
  float* stats= (float*)(ws + off); off += 256 * 4;
  double* part= (double*)(ws + off); off += 256 * 8;

  const int T64 = NROWS * 64;          // 2097152
  const int T3  = NROWS * 3;           // 98304
  const int KNN_GRID = NROWS / 16;     // 2048 blocks

  // ---- layer 1 (F=3 -> 64) ----
  sqnorm_kernel<<<NROWS / 256, 256, 0, stream>>>(x, sq, 3);
  knn_tiled<3><<<KNN_GRID, 256, 0, stream>>>(x, sq, idxb);
  mlp_pc_kernel<<<T64 / 256, 256, 0, stream>>>(x, W1, b1, P, CA, 3, 64, T64);
  aggregate_kernel<<<T64 / 256, 256, 0, stream>>>(idxb, P, CA, 64, T64);
  bn_stats_kernel<<<64, 256, 0, stream>>>(CA, stats);
  bn_apply_kernel<<<T64 / 256, 256, 0, stream>>>(CA, stats, g1, be1, CA, T64);

  // ---- layer 2 (F=64 -> 64) ----
  sqnorm_kernel<<<NROWS / 256, 256, 0, stream>>>(CA, sq, 64);
  knn_tiled<64><<<KNN_GRID, 256, 0, stream>>>(CA, sq, idxb);
  mlp_pc_kernel<<<T64 / 256, 256, 0, stream>>>(CA, W2, b2, P, CB, 64, 64, T64);
  aggregate_kernel<<<T64 / 256, 256, 0, stream>>>(idxb, P, CB, 64, T64);
  bn_stats_kernel<<<64, 256, 0, stream>>>(CB, stats);
  bn_apply_kernel<<<T64 / 256, 256, 0, stream>>>(CB, stats, g2, be2, CB, T64);

  // ---- layer 3 (F=64 -> 3, no relu/bn) ----
  sqnorm_kernel<<<NROWS / 256, 256, 0, stream>>>(CB, sq, 64);
  knn_tiled<64><<<KNN_GRID, 256, 0, stream>>>(CB, sq, idxb);
  mlp_pc_kernel<<<T3 / 256, 256, 0, stream>>>(CB, W3, b3, P, CA, 64, 3, T3);
  aggregate_kernel<<<T3 / 256, 256, 0, stream>>>(idxb, P, CA, 3, T3);

  // ---- output + loss ----
  final_kernel<<<256, 256, 0, stream>>>(CA, tgt, out, part);
  loss_kernel<<<1, 256, 0, stream>>>(part, out);
}